// Round 1
// baseline (106.892 us; speedup 1.0000x reference)
//
#include <hip/hip_runtime.h>

// LIF spike forward.
// x: [T=8, B=64, C=128, H=32, W=32] fp32, out: same shape fp32.
// Recurrence over T only; spatial elements independent.
//   mem = 0.25*mem + x_t; spike = (mem - 1 > 0); mem *= (1 - spike)
// Memory-bound: 256 MiB in + 256 MiB out -> ~85us floor at 6.3 TB/s.

#define LIF_T 8
#define LIF_TAU 0.25f
#define LIF_TH 1.0f

__global__ __launch_bounds__(256) void lif_fwd_kernel(
    const float4* __restrict__ x, float4* __restrict__ out, int n4) {
    int i = blockIdx.x * blockDim.x + threadIdx.x;
    if (i >= n4) return;

    // Preload all T slices (independent loads -> memory-level parallelism).
    float4 xv[LIF_T];
#pragma unroll
    for (int t = 0; t < LIF_T; ++t) {
        xv[t] = x[(size_t)t * (size_t)n4 + (size_t)i];
    }

    float mx = 0.0f, my = 0.0f, mz = 0.0f, mw = 0.0f;
#pragma unroll
    for (int t = 0; t < LIF_T; ++t) {
        float4 s;
        mx = fmaf(LIF_TAU, mx, xv[t].x);
        s.x = (mx > LIF_TH) ? 1.0f : 0.0f;
        mx *= (1.0f - s.x);

        my = fmaf(LIF_TAU, my, xv[t].y);
        s.y = (my > LIF_TH) ? 1.0f : 0.0f;
        my *= (1.0f - s.y);

        mz = fmaf(LIF_TAU, mz, xv[t].z);
        s.z = (mz > LIF_TH) ? 1.0f : 0.0f;
        mz *= (1.0f - s.z);

        mw = fmaf(LIF_TAU, mw, xv[t].w);
        s.w = (mw > LIF_TH) ? 1.0f : 0.0f;
        mw *= (1.0f - s.w);

        out[(size_t)t * (size_t)n4 + (size_t)i] = s;
    }
}

extern "C" void kernel_launch(void* const* d_in, const int* in_sizes, int n_in,
                              void* d_out, int out_size, void* d_ws, size_t ws_size,
                              hipStream_t stream) {
    const float* x = (const float*)d_in[0];
    float* out = (float*)d_out;

    // total elements = T * N_spatial; out_size == in_sizes[0]
    const int total = in_sizes[0];
    const int n_spatial = total / LIF_T;   // 8,388,608
    const int n4 = n_spatial / 4;          // 2,097,152 float4 per t-slice

    const int block = 256;
    const int grid = (n4 + block - 1) / block;  // 8192 blocks

    lif_fwd_kernel<<<grid, block, 0, stream>>>(
        (const float4*)x, (float4*)out, n4);
}

// Round 3
// 84.121 us; speedup vs baseline: 1.2707x; 1.2707x over previous
//
#include <hip/hip_runtime.h>

// LIF spike forward.
// x: [T=8, B=64, C=128, H=32, W=32] fp32, out: same shape fp32.
// Recurrence over T only; spatial elements independent.
//   mem = 0.25*mem + x_t; spike = (mem - 1 > 0); mem *= (1 - spike)
// Memory-bound: 256 MiB in + 256 MiB out.
// R1: 106.9us = 5.02 TB/s effective (copy ceiling 6.29 TB/s, floor ~85us).
// R2: nontemporal store on HIP float4 failed to compile (struct, not native
//     vector). R3: same plan via ext_vector_type(4) float — write-once out
//     bypasses L2/L3 so it stops evicting x (x = 256 MiB = exactly L3 size).

#define LIF_T 8
#define LIF_TAU 0.25f
#define LIF_TH 1.0f

typedef float floatx4 __attribute__((ext_vector_type(4)));

__global__ __launch_bounds__(256) void lif_fwd_kernel(
    const floatx4* __restrict__ x, floatx4* __restrict__ out, int n4) {
    int i = blockIdx.x * blockDim.x + threadIdx.x;
    if (i >= n4) return;

    // Preload all T slices (independent loads -> memory-level parallelism).
    floatx4 xv[LIF_T];
#pragma unroll
    for (int t = 0; t < LIF_T; ++t) {
        xv[t] = x[(size_t)t * (size_t)n4 + (size_t)i];
    }

    float mx = 0.0f, my = 0.0f, mz = 0.0f, mw = 0.0f;
#pragma unroll
    for (int t = 0; t < LIF_T; ++t) {
        floatx4 s;
        mx = fmaf(LIF_TAU, mx, xv[t].x);
        s.x = (mx > LIF_TH) ? 1.0f : 0.0f;
        mx *= (1.0f - s.x);

        my = fmaf(LIF_TAU, my, xv[t].y);
        s.y = (my > LIF_TH) ? 1.0f : 0.0f;
        my *= (1.0f - s.y);

        mz = fmaf(LIF_TAU, mz, xv[t].z);
        s.z = (mz > LIF_TH) ? 1.0f : 0.0f;
        mz *= (1.0f - s.z);

        mw = fmaf(LIF_TAU, mw, xv[t].w);
        s.w = (mw > LIF_TH) ? 1.0f : 0.0f;
        mw *= (1.0f - s.w);

        // Write-once output: bypass caches so it doesn't evict x.
        __builtin_nontemporal_store(s, &out[(size_t)t * (size_t)n4 + (size_t)i]);
    }
}

extern "C" void kernel_launch(void* const* d_in, const int* in_sizes, int n_in,
                              void* d_out, int out_size, void* d_ws, size_t ws_size,
                              hipStream_t stream) {
    const float* x = (const float*)d_in[0];
    float* out = (float*)d_out;

    // total elements = T * N_spatial; out_size == in_sizes[0]
    const int total = in_sizes[0];
    const int n_spatial = total / LIF_T;   // 8,388,608
    const int n4 = n_spatial / 4;          // 2,097,152 float4 per t-slice

    const int block = 256;
    const int grid = (n4 + block - 1) / block;  // 8192 blocks

    lif_fwd_kernel<<<grid, block, 0, stream>>>(
        (const floatx4*)x, (floatx4*)out, n4);
}